// Round 3
// baseline (101.054 us; speedup 1.0000x reference)
//
#include <hip/hip_runtime.h>

// Problem constants (match reference)
#define C_   64
#define H_   256
#define W_   256
#define L0_  1024   // j axis (g0 -> y taps)
#define L1_  1024   // i axis (g1 -> x taps)
#define JT   32     // j-tile per block

// Bicubic taps/weights, matches PyTorch grid_sample
// (bicubic, padding_mode='border', align_corners=True), A = -0.75.
__device__ __forceinline__ void cubic_prep(float g, int size, int idx[4], float w[4]) {
    const float A = -0.75f;
    float x  = (g + 1.0f) * 0.5f * (float)(size - 1);   // align_corners=True
    float x0 = floorf(x);
    float t  = x - x0;
    int   ix = (int)x0;
    float t2 = t * t, t3 = t2 * t;
    w[0] = A * (t3 - 2.0f * t2 + t);
    w[1] = (A + 2.0f) * t3 - (A + 3.0f) * t2 + 1.0f;
    float s = 1.0f - t, s2 = s * s;
    w[2] = (A + 2.0f) * s2 * s - (A + 3.0f) * s2 + 1.0f;
    float u = 2.0f - t, u2 = u * u;
    w[3] = A * u2 * u - 5.0f * A * u2 + 8.0f * A * u - 4.0f * A;
    idx[0] = min(max(ix - 1, 0), size - 1);   // border clamp
    idx[1] = min(max(ix,     0), size - 1);
    idx[2] = min(max(ix + 1, 0), size - 1);
    idx[3] = min(max(ix + 2, 0), size - 1);
}

// Quad-granular swizzle: bijective on the low 3 bits within any 8 consecutive
// x, so both the phase-1 b128 quad-writes and phase-2 b128 quad-gathers hit
// all 32 banks per 8-lane group (exactly the wave64-b128 minimum, 0 conflicts).
__device__ __forceinline__ int swq(int x) { return (x ^ (x >> 3)) & 7; }

// Y-FIRST separable bicubic, quad-j LDS layout.
//   hy[x][q][m]: q = (quad ^ swq(x)), m = j within quad. One ds_read_b128
//   fetches 4 j's worth of a tap -> phase-2 LDS cost drops from ~41 cyc/64
//   outputs (b32 taps) to ~16.5 cyc/64 (b128 taps), below the HBM-write floor.
//   Single kernel, tables in LDS (no prologue launch, no VMEM latency on the
//   phase-2 critical path), round-1 grid & occupancy (3 blocks/CU @ 52 KB).
__global__ __launch_bounds__(256, 3) void bicubic_yquad(const float* __restrict__ v,
                                                        const float* __restrict__ g0,
                                                        const float* __restrict__ g1,
                                                        float* __restrict__ out) {
    __shared__ float        hy[H_ * JT];   // 32 KB
    __shared__ float4       xw[L1_];       // 16 KB: x weights per i
    __shared__ unsigned int xip[L1_];      //  4 KB: packed clamped x-tap idx per i

    const int t  = threadIdx.x;
    const int c  = blockIdx.y;
    const int j0 = blockIdx.x * JT;

    // ---- x-tap tables, 4 i's per thread (shared by all 1024 i of phase 2) ----
    {
        const int ib = t * 4;
#pragma unroll
        for (int s = 0; s < 4; ++s) {
            int i = ib + s;
            int xi4[4]; float w4[4];
            cubic_prep(g1[i], W_, xi4, w4);
            xw[i]  = make_float4(w4[0], w4[1], w4[2], w4[3]);
            xip[i] = (unsigned)xi4[0] | ((unsigned)xi4[1] << 8)
                   | ((unsigned)xi4[2] << 16) | ((unsigned)xi4[3] << 24);
        }
    }

    const int lane = t & 63;
    const int wv   = t >> 6;

    // ---- phase 1: y-interp 4 j's (one quad) at a time; float4 row loads ----
    {
        const int x4 = lane * 4;               // lane covers x4..x4+3
        const float* vc = v + (size_t)c * (H_ * W_);
#pragma unroll
        for (int qq = 0; qq < 2; ++qq) {       // wave owns 2 quads (8 j)
            const int qg = wv * 2 + qq;        // quad index in tile, 0..7
            float acc[4][4];                   // [m = j-in-quad][k = x-in-four]
#pragma unroll
            for (int m = 0; m < 4; ++m) {
                int yi4[4]; float wy4[4];
                cubic_prep(g0[j0 + qg * 4 + m], H_, yi4, wy4);
                float4 r0 = *reinterpret_cast<const float4*>(vc + yi4[0] * W_ + x4);
                float4 r1 = *reinterpret_cast<const float4*>(vc + yi4[1] * W_ + x4);
                float4 r2 = *reinterpret_cast<const float4*>(vc + yi4[2] * W_ + x4);
                float4 r3 = *reinterpret_cast<const float4*>(vc + yi4[3] * W_ + x4);
#pragma unroll
                for (int k = 0; k < 4; ++k)
                    acc[m][k] = wy4[0] * (&r0.x)[k] + wy4[1] * (&r1.x)[k]
                              + wy4[2] * (&r2.x)[k] + wy4[3] * (&r3.x)[k];
            }
#pragma unroll
            for (int k = 0; k < 4; ++k) {      // transpose -> quad write
                const int x = x4 + k;
                *reinterpret_cast<float4*>(&hy[x * JT + ((qg ^ swq(x)) << 2)]) =
                    make_float4(acc[0][k], acc[1][k], acc[2][k], acc[3][k]);
            }
        }
    }
    __syncthreads();

    // ---- phase 2: x-interp; lane owns a j-QUAD; taps are ds_read_b128 ----
    {
        const int jq   = lane & 7;             // quad slot in tile
        const int isub = lane >> 3;            // 8 i's per wave-instr
        float* op = out + (size_t)c * ((size_t)L1_ * L0_) + j0 + jq * 4;
        int i = wv * 256 + isub;               // wave owns 256 consecutive i
#pragma unroll 4
        for (int it = 0; it < 32; ++it, i += 8) {
            const unsigned p = xip[i];         // 8 distinct addrs -> 1 pass
            const float4   w = xw[i];
            const int xa = p & 255, xb = (p >> 8) & 255,
                      xc = (p >> 16) & 255, xd = p >> 24;
            const float4 va = *reinterpret_cast<const float4*>(&hy[xa * JT + ((jq ^ swq(xa)) << 2)]);
            const float4 vb = *reinterpret_cast<const float4*>(&hy[xb * JT + ((jq ^ swq(xb)) << 2)]);
            const float4 vg = *reinterpret_cast<const float4*>(&hy[xc * JT + ((jq ^ swq(xc)) << 2)]);
            const float4 vd = *reinterpret_cast<const float4*>(&hy[xd * JT + ((jq ^ swq(xd)) << 2)]);
            float4 o;
            o.x = w.x * va.x + w.y * vb.x + w.z * vg.x + w.w * vd.x;
            o.y = w.x * va.y + w.y * vb.y + w.z * vg.y + w.w * vd.y;
            o.z = w.x * va.z + w.y * vb.z + w.z * vg.z + w.w * vd.z;
            o.w = w.x * va.w + w.y * vb.w + w.z * vg.w + w.w * vd.w;
            *reinterpret_cast<float4*>(op + (size_t)i * L0_) = o;  // coalesced
        }
    }
}

extern "C" void kernel_launch(void* const* d_in, const int* in_sizes, int n_in,
                              void* d_out, int out_size, void* d_ws, size_t ws_size,
                              hipStream_t stream) {
    const float* values = (const float*)d_in[0];  // (1, C, H, W) fp32
    const float* g0     = (const float*)d_in[1];  // (L0,) fp32 -> y axis
    const float* g1     = (const float*)d_in[2];  // (L1,) fp32 -> x axis
    float* out          = (float*)d_out;          // (1, C, L1, L0) fp32

    dim3 grid(L0_ / JT, C_);   // (32, 64) = 2048 blocks
    bicubic_yquad<<<grid, 256, 0, stream>>>(values, g0, g1, out);
}